// Round 5
// baseline (15.055 us; speedup 1.0000x reference)
//
#include <hip/hip_runtime.h>
#include <hip/hip_bf16.h>

// Embedding gather with OOV handling.
// out[r][d] = (idx[r] >= VOCAB) ? oov[d] : emb[idx[r]][d]
// D = 200 floats = 50 float4 per row; rows are 800B => 16B aligned.
//
// R5: inverse of R4's failed experiment. R4 (cached loads + cached stores,
// 13.47us) thrashed L2 with 52MB of mixed traffic. R2 (cached loads + NT
// stores, 11.87us) pays a mandatory 26.2MB HBM write drain every replay.
// Here: NT (evict-first) GATHER loads + CACHED stores. The output (26.2MB,
// ~3.3MB/XCD) is overwritten in place every graph replay, so if its dirty
// lines stay resident in L2, steady-state HBM write traffic ~0 and stores
// complete at L2 speed. Gather reads have only ~1.27x reuse per replay and
// are L3-resident anyway -> evict-first costs nothing.
// Index loads stay fully cached (hot, reused across lanes).

typedef float f32x4 __attribute__((ext_vector_type(4)));

#define ELEMS 4
#define BLOCK 256

__global__ void embed_gather_kernel(const int* __restrict__ indices,
                                    const f32x4* __restrict__ emb,
                                    const f32x4* __restrict__ oov,
                                    f32x4* __restrict__ out,
                                    int n_vec,      // total float4 elements in output
                                    int vocab) {
    int base = blockIdx.x * (BLOCK * ELEMS) + threadIdx.x;

    int   idx[ELEMS];
    int   off[ELEMS];
    f32x4 val[ELEMS];

    // Phase 1: index loads (cached; L1-hot, shared across lanes)
    #pragma unroll
    for (int k = 0; k < ELEMS; ++k) {
        int i = base + k * BLOCK;
        int ii = (i < n_vec) ? i : 0;
        int row = ii / 50;          // magic-mul, cheap
        off[k] = ii - row * 50;
        idx[k] = indices[row];
    }

    // Phase 2: gather loads, non-temporal (evict-first in L2; low reuse,
    // L3 keeps the table warm across replays)
    #pragma unroll
    for (int k = 0; k < ELEMS; ++k) {
        const f32x4* src = (idx[k] >= vocab)
                         ? (oov + off[k])
                         : (emb + (long long)idx[k] * 50 + off[k]);
        val[k] = __builtin_nontemporal_load(src);
    }

    // Phase 3: cached stores — complete at L2; dirty output lines stay
    // resident across replays (output < L2 capacity), killing HBM writes.
    #pragma unroll
    for (int k = 0; k < ELEMS; ++k) {
        int i = base + k * BLOCK;
        if (i < n_vec) {
            out[i] = val[k];
        }
    }
}

extern "C" void kernel_launch(void* const* d_in, const int* in_sizes, int n_in,
                              void* d_out, int out_size, void* d_ws, size_t ws_size,
                              hipStream_t stream) {
    const int*   indices = (const int*)d_in[0];
    const float* emb     = (const float*)d_in[1];
    const float* oov     = (const float*)d_in[2];
    float*       out     = (float*)d_out;

    const int D      = in_sizes[2];            // 200
    const int vocab  = in_sizes[1] / D;        // 100000
    const int n_vec  = out_size / 4;           // float4 count

    const int grid = (n_vec + BLOCK * ELEMS - 1) / (BLOCK * ELEMS);
    embed_gather_kernel<<<grid, BLOCK, 0, stream>>>(
        indices,
        (const f32x4*)emb,
        (const f32x4*)oov,
        (f32x4*)out,
        n_vec, vocab);
}